// Round 7
// baseline (142.219 us; speedup 1.0000x reference)
//
#include <hip/hip_runtime.h>
#include <hip/hip_bf16.h>
#include <hip/hip_cooperative_groups.h>

namespace cg = cooperative_groups;

// ClassBalancedSupConLoss, B=8192, D=128 — single cooperative kernel.
// loss_i = -(BASE/t_i)*[P_i - C_i*lse_i]/(C_i+eps)
//   P_i   = invt_i*(e_i.S_{c(i)} - ||e_i||^2)      (fp32 closed form)
//   C_i   = count_{c(i)} - 1
//   lse_i = invt_i*||e_i||^2 + ln(Z_i),  Z_i = sum_j exp2(v_ij - m_i),
//           m_i = invt_i*log2e*||e_i||^2 (fixed reference; identity exact
//           for any fixed m; self-logit dominates -> no overflow)
// Phases (grid-stride, grid.sync between):
//   A: cast E -> Ebf (tiled, validated r4) and Ebs (pre-scaled by
//      invt*log2e), row norms, per-group class-sum/count partials.
//   B: blocks 0-3 reduce S/counts; all blocks run k2 units
//      (32x32x16 bf16 MFMA, swapped operands, DUAL accumulator chains).
//   C: per-row loss -> per-block partials.  D: block 0 -> out.
// No atomics, no memset: every buffer fully overwritten each launch.

#define B_ROWS 8192
#define D_DIM 128
#define NSPLIT 32
#define JRANGE (B_ROWS / NSPLIT)       // 256
#define NSTEPS (JRANGE / 32)           // 8
#define NUNITS (64 * NSPLIT)           // 2048
#define BASE_TEMP 0.07f
#define LOG2E 1.4426950408889634f
#define LN2 0.6931471805599453f

typedef __bf16 bf16x8 __attribute__((ext_vector_type(8)));
typedef __bf16 bf16x4 __attribute__((ext_vector_type(4)));
typedef float floatx16 __attribute__((ext_vector_type(16)));

__device__ __forceinline__ float class_invtemp(int lbl) {
    return (lbl == 0) ? 12.5f : ((lbl == 1) ? 20.0f : 10.0f);
}

__global__ __launch_bounds__(256, 3) void supcon_all(
        const float* __restrict__ E, const int* __restrict__ labels,
        __bf16* __restrict__ Ebf, __bf16* __restrict__ Ebs,
        float* __restrict__ nrm,
        float* __restrict__ Spart /*[256][3][128]*/,
        int* __restrict__ cntpart /*[256][4]*/,
        float* __restrict__ S /*[3][128]*/, float* __restrict__ counts /*[4]*/,
        float* __restrict__ part /*[NSPLIT][B]*/,
        float* __restrict__ bpart /*[256][2]*/, float* __restrict__ out) {
    cg::grid_group gg = cg::this_grid();
    const int tid = threadIdx.x;
    const int bid = blockIdx.x;
    const int nblk = gridDim.x;

    __shared__ float sh[3][128];      // A: class partials; C: staged S
    __shared__ int scnt[3];
    __shared__ float rl[4];
    __shared__ int rv[4];

    // ================= Phase A =================
    for (int g = bid; g < 256; g += nblk) {
        const int row0 = g * 32;
        if (tid < 3) scnt[tid] = 0;
        __syncthreads();
        const float4* src = reinterpret_cast<const float4*>(E + (size_t)row0 * D_DIM);
        #pragma unroll
        for (int p = 0; p < 4; ++p) {
            int idx = p * 256 + tid;             // 1024 float4 = 32 rows x 32 k4
            float4 v = src[idx];
            int r = idx >> 5, k4 = idx & 31;
            int R = row0 + r;
            float sc = class_invtemp(labels[R]) * LOG2E;
            int T = R >> 5;
            int l = (R & 31) + ((k4 >> 1) & 1) * 32;
            int c = k4 >> 2;
            size_t dst = (size_t)T * 4096 + c * 512 + l * 8 + (k4 & 1) * 4;
            bf16x4 o  = { (__bf16)v.x, (__bf16)v.y, (__bf16)v.z, (__bf16)v.w };
            bf16x4 os = { (__bf16)(v.x * sc), (__bf16)(v.y * sc),
                          (__bf16)(v.z * sc), (__bf16)(v.w * sc) };
            *reinterpret_cast<bf16x4*>(Ebf + dst) = o;
            *reinterpret_cast<bf16x4*>(Ebs + dst) = os;
            float s = v.x * v.x + v.y * v.y + v.z * v.z + v.w * v.w;
            s += __shfl_xor(s, 1);  s += __shfl_xor(s, 2);  s += __shfl_xor(s, 4);
            s += __shfl_xor(s, 8);  s += __shfl_xor(s, 16);
            if ((tid & 31) == 0) nrm[R] = s;     // 32 lanes hold one full row
        }
        // per-group class sums (two halves of 16 rows)
        const int d = tid & 127, half = tid >> 7;
        float s0 = 0.f, s1 = 0.f, s2 = 0.f;
        #pragma unroll 4
        for (int r2 = 0; r2 < 16; ++r2) {
            int r = row0 + half * 16 + r2;
            float v = E[(size_t)r * D_DIM + d];
            int l = labels[r];
            s0 += (l == 0) ? v : 0.f;
            s1 += (l == 1) ? v : 0.f;
            s2 += (l == 2) ? v : 0.f;
        }
        if (half == 1) { sh[0][d] = s0; sh[1][d] = s1; sh[2][d] = s2; }
        if (tid < 32) atomicAdd(&scnt[labels[row0 + tid]], 1);  // LDS int: exact
        __syncthreads();
        if (half == 0) {
            Spart[((size_t)g * 3 + 0) * 128 + d] = s0 + sh[0][d];
            Spart[((size_t)g * 3 + 1) * 128 + d] = s1 + sh[1][d];
            Spart[((size_t)g * 3 + 2) * 128 + d] = s2 + sh[2][d];
        }
        if (tid < 3) cntpart[g * 4 + tid] = scnt[tid];
        __syncthreads();
    }
    gg.sync();

    // ================= Phase B0: reduce S / counts (blocks 0..3) ========
    if (bid < 3) {
        if (tid < 128) {
            float a = 0.f;
            #pragma unroll 8
            for (int g = 0; g < 256; ++g)
                a += Spart[((size_t)g * 3 + bid) * 128 + tid];
            S[bid * 128 + tid] = a;
        }
    } else if (bid == 3 && tid < 3) {
        int a = 0;
        #pragma unroll 8
        for (int g = 0; g < 256; ++g) a += cntpart[g * 4 + tid];
        counts[tid] = (float)a;
    }

    // ================= Phase B: k2 units (dual-chain MFMA) =============
    for (int u = bid; u < NUNITS; u += nblk) {
        const int itile = u >> 5;        // 0..63
        const int split = u & 31;
        const int j0 = split * JRANGE;
        const int lane = tid & 63;
        const int wave = tid >> 6;
        const int col = lane & 31;
        const int icol = itile * 128 + wave * 32 + col;

        const float bscale = class_invtemp(labels[icol]) * LOG2E;
        const float negm = -bscale * nrm[icol];

        const int iT = itile * 4 + wave;
        const __bf16* bbase = Ebs + (size_t)iT * 4096 + lane * 8;  // pre-scaled
        bf16x8 Bf[8];
        #pragma unroll
        for (int c = 0; c < 8; ++c)
            Bf[c] = *reinterpret_cast<const bf16x8*>(bbase + c * 512);

        const __bf16* abase = Ebf + ((size_t)(j0 >> 5)) * 4096 + lane * 8;
        bf16x8 A0[8], A1[8];
        #pragma unroll
        for (int c = 0; c < 8; ++c)
            A0[c] = *reinterpret_cast<const bf16x8*>(abase + c * 512);

        float Zacc[8];
        #pragma unroll
        for (int r = 0; r < 8; ++r) Zacc[r] = 0.f;

        auto k2_step = [&](const bf16x8* Ab) {
            floatx16 a0, a1;
            #pragma unroll
            for (int r = 0; r < 16; ++r) { a0[r] = negm; a1[r] = 0.f; }
            a0 = __builtin_amdgcn_mfma_f32_32x32x16_bf16(Ab[0], Bf[0], a0, 0, 0, 0);
            a1 = __builtin_amdgcn_mfma_f32_32x32x16_bf16(Ab[4], Bf[4], a1, 0, 0, 0);
            a0 = __builtin_amdgcn_mfma_f32_32x32x16_bf16(Ab[1], Bf[1], a0, 0, 0, 0);
            a1 = __builtin_amdgcn_mfma_f32_32x32x16_bf16(Ab[5], Bf[5], a1, 0, 0, 0);
            a0 = __builtin_amdgcn_mfma_f32_32x32x16_bf16(Ab[2], Bf[2], a0, 0, 0, 0);
            a1 = __builtin_amdgcn_mfma_f32_32x32x16_bf16(Ab[6], Bf[6], a1, 0, 0, 0);
            a0 = __builtin_amdgcn_mfma_f32_32x32x16_bf16(Ab[3], Bf[3], a0, 0, 0, 0);
            a1 = __builtin_amdgcn_mfma_f32_32x32x16_bf16(Ab[7], Bf[7], a1, 0, 0, 0);
            #pragma unroll
            for (int r8 = 0; r8 < 8; ++r8) {
                float z = __builtin_amdgcn_exp2f(a0[2 * r8] + a1[2 * r8])
                        + __builtin_amdgcn_exp2f(a0[2 * r8 + 1] + a1[2 * r8 + 1]);
                Zacc[r8] += z;
            }
        };

        for (int s = 0; s < NSTEPS; s += 2) {
            {   // consume A0 (step s), prefetch s+1 -> A1
                const __bf16* ap = abase + (size_t)(s + 1) * 4096;
                #pragma unroll
                for (int c = 0; c < 8; ++c)
                    A1[c] = *reinterpret_cast<const bf16x8*>(ap + c * 512);
                k2_step(A0);
            }
            {   // consume A1 (step s+1), prefetch s+2 -> A0
                if (s + 2 < NSTEPS) {
                    const __bf16* ap = abase + (size_t)(s + 2) * 4096;
                    #pragma unroll
                    for (int c = 0; c < 8; ++c)
                        A0[c] = *reinterpret_cast<const bf16x8*>(ap + c * 512);
                }
                k2_step(A1);
            }
        }

        float t0 = (Zacc[0] + Zacc[1]) + (Zacc[2] + Zacc[3]);
        float t1 = (Zacc[4] + Zacc[5]) + (Zacc[6] + Zacc[7]);
        float Zt = t0 + t1;
        Zt += __shfl_xor(Zt, 32);       // lanes l, l+32 hold same i-col
        if (lane < 32)
            part[(size_t)split * B_ROWS + icol] = Zt;
    }
    gg.sync();

    // ================= Phase C: per-row loss -> block partials =========
    if (tid < 128) {                    // stage S into shared (alias sh)
        sh[0][tid] = S[tid];
        sh[1][tid] = S[128 + tid];
        sh[2][tid] = S[256 + tid];
    }
    __syncthreads();
    for (int v = bid; v < 256; v += nblk) {
        const int r = tid >> 3, g = tid & 7;     // 32 rows/block, 8 thr/row
        const int i = v * 32 + r;
        const int lab = labels[i];
        const float invt = class_invtemp(lab);

        const float4* er = reinterpret_cast<const float4*>(E + (size_t)i * D_DIM);
        const float4* sr = reinterpret_cast<const float4*>(&sh[lab][0]);
        float dotS = 0.f;
        #pragma unroll
        for (int q = 0; q < 4; ++q) {
            float4 vv = er[g * 4 + q];
            float4 ss = sr[g * 4 + q];
            dotS += vv.x * ss.x + vv.y * ss.y + vv.z * ss.z + vv.w * ss.w;
        }
        float Zp = 0.f;
        #pragma unroll
        for (int p = 0; p < NSPLIT / 8; ++p)
            Zp += part[(size_t)(g + p * 8) * B_ROWS + i];

        #pragma unroll
        for (int off = 1; off < 8; off <<= 1) {
            dotS += __shfl_xor(dotS, off);
            Zp   += __shfl_xor(Zp, off);
        }

        float loss = 0.f;
        int valid = 0;
        if (g == 0) {
            const float nr = nrm[i];
            const float C = counts[lab] - 1.0f;
            const float lse = invt * nr + LN2 * __builtin_amdgcn_logf(Zp);
            const float P_nat = invt * (dotS - nr);
            if (C > 0.f) {
                loss = -(BASE_TEMP * invt) * (P_nat - C * lse) / (C + 1e-8f);
                valid = 1;
            }
        }
        loss += __shfl_down(loss, 8);   valid += __shfl_down(valid, 8);
        loss += __shfl_down(loss, 16);  valid += __shfl_down(valid, 16);
        loss += __shfl_down(loss, 32);  valid += __shfl_down(valid, 32);
        if ((tid & 63) == 0) { rl[tid >> 6] = loss; rv[tid >> 6] = valid; }
        __syncthreads();
        if (tid == 0) {
            bpart[v * 2 + 0] = (rl[0] + rl[1]) + (rl[2] + rl[3]);
            bpart[v * 2 + 1] = (float)((rv[0] + rv[1]) + (rv[2] + rv[3]));
        }
        __syncthreads();
    }
    gg.sync();

    // ================= Phase D: final scalar ===========================
    if (bid == 0) {
        float T = bpart[tid * 2], N = bpart[tid * 2 + 1];
        #pragma unroll
        for (int off = 32; off; off >>= 1) {
            T += __shfl_down(T, off);
            N += __shfl_down(N, off);
        }
        if ((tid & 63) == 0) { rl[tid >> 6] = T; rv[tid >> 6] = (int)N; }
        __syncthreads();
        if (tid == 0) {
            float Tt = (rl[0] + rl[1]) + (rl[2] + rl[3]);
            float Nt = (float)((rv[0] + rv[1]) + (rv[2] + rv[3]));
            out[0] = (Nt > 0.f) ? Tt / fmaxf(Nt, 1.f) : 0.f;
        }
    }
}

extern "C" void kernel_launch(void* const* d_in, const int* in_sizes, int n_in,
                              void* d_out, int out_size, void* d_ws, size_t ws_size,
                              hipStream_t stream) {
    const float* E = (const float*)d_in[0];
    const int* labels = (const int*)d_in[1];
    float* out = (float*)d_out;
    char* ws = (char*)d_ws;

    // workspace layout (~6 MB total)
    const size_t OFF_EBF   = 0;                       // 2 MB tiled bf16
    const size_t OFF_EBS   = (size_t)2 << 20;         // 2 MB tiled bf16 (scaled)
    const size_t OFF_NRM   = (size_t)4 << 20;         // 32 KB
    const size_t OFF_SPART = OFF_NRM + 32768;         // 384 KB
    const size_t OFF_CNTP  = OFF_SPART + 393216;      // 4 KB
    const size_t OFF_S     = OFF_CNTP + 4096;         // 1.5 KB
    const size_t OFF_CNT   = OFF_S + 2048;            // 64 B
    const size_t OFF_BPART = OFF_CNT + 64;            // 2 KB
    const size_t OFF_PART  = (size_t)5 << 20;         // 1 MB (32 x 8192 f32)

    const float* Ec = E;
    const int* lc = labels;
    __bf16* Ebf = (__bf16*)(ws + OFF_EBF);
    __bf16* Ebs = (__bf16*)(ws + OFF_EBS);
    float* nrm = (float*)(ws + OFF_NRM);
    float* Spart = (float*)(ws + OFF_SPART);
    int* cntpart = (int*)(ws + OFF_CNTP);
    float* S = (float*)(ws + OFF_S);
    float* counts = (float*)(ws + OFF_CNT);
    float* bpart = (float*)(ws + OFF_BPART);
    float* part = (float*)(ws + OFF_PART);

    int occ = 0;
    if (hipOccupancyMaxActiveBlocksPerMultiprocessor(
            &occ, (const void*)supcon_all, 256, 0) != hipSuccess || occ < 1)
        occ = 1;
    if (occ > 3) occ = 3;
    dim3 grid(256 * occ);

    void* args[] = { (void*)&Ec, (void*)&lc, (void*)&Ebf, (void*)&Ebs,
                     (void*)&nrm, (void*)&Spart, (void*)&cntpart, (void*)&S,
                     (void*)&counts, (void*)&part, (void*)&bpart, (void*)&out };
    hipLaunchCooperativeKernel((const void*)supcon_all, grid, dim3(256),
                               args, 0, stream);
}